// Round 1
// baseline (4541.820 us; speedup 1.0000x reference)
//
#include <hip/hip_runtime.h>
#include <cstdint>

#define NPROD 100000
#define KU 256
#define NBASK 64
#define MBS 20
#define BITEMS 1280
#define HD 256
#define G3 768
#define TT 64

typedef short v8s __attribute__((ext_vector_type(8)));
typedef float v4f __attribute__((ext_vector_type(4)));

__device__ __forceinline__ unsigned short f2b(float f){
  uint32_t u = __float_as_uint(f);
  u += 0x7FFFu + ((u >> 16) & 1u);
  return (unsigned short)(u >> 16);
}
__device__ __forceinline__ float b2f(unsigned short s){
  return __uint_as_float(((uint32_t)s) << 16);
}

// ---------------- weight conversion: fp32 -> bf16 (hi) and residual (lo) ----
__global__ __launch_bounds__(1024) void k_convert(
    const float* __restrict__ wih, const float* __restrict__ whh,
    unsigned short* __restrict__ wih1b,
    unsigned short* __restrict__ wih2hi, unsigned short* __restrict__ wih2lo,
    unsigned short* __restrict__ whh1hi, unsigned short* __restrict__ whh1lo,
    unsigned short* __restrict__ whh2hi, unsigned short* __restrict__ whh2lo)
{
  int idx = blockIdx.x * 1024 + threadIdx.x;     // 0..196607
  int which = blockIdx.y;
  if (which == 0) {
    wih1b[idx] = f2b(wih[idx]);
  } else if (which == 1) {
    float v = wih[196608 + idx];
    unsigned short hi = f2b(v);
    wih2hi[idx] = hi; wih2lo[idx] = f2b(v - b2f(hi));
  } else if (which == 2) {
    float v = whh[idx];
    unsigned short hi = f2b(v);
    whh1hi[idx] = hi; whh1lo[idx] = f2b(v - b2f(hi));
  } else {
    float v = whh[196608 + idx];
    unsigned short hi = f2b(v);
    whh2hi[idx] = hi; whh2lo[idx] = f2b(v - b2f(hi));
  }
}

// ---------------- per-user basket ordering (stable: valid first) -----------
__global__ __launch_bounds__(64) void k_order(
    const float* __restrict__ prob, const int* __restrict__ seq,
    int* __restrict__ order, int* __restrict__ lengths)
{
  int k = blockIdx.x, j = threadIdx.x;           // j = basket
  int base = k * BITEMS + j * MBS;
  float mx = 0.f;
  #pragma unroll
  for (int m = 0; m < MBS; m++) {
    int it = seq[base + m];
    float p = (it >= 0) ? prob[base + m] : 0.f;
    mx = fmaxf(mx, p);
  }
  bool valid = mx > 0.f;
  unsigned long long bal = __ballot(valid);
  int len = __popcll(bal);
  unsigned long long below = bal & ((1ull << j) - 1ull);
  int pos = valid ? __popcll(below) : (len + (j - __popcll(below)));
  order[k * NBASK + j] = pos;
  if (j == 0) lengths[k] = (len > 0) ? len : 1;
}

// ---------------- basket pooling -> ordered x (bf16) -----------------------
__global__ __launch_bounds__(256) void k_basket(
    const float* __restrict__ prob, const int* __restrict__ seq,
    const float* __restrict__ table, const int* __restrict__ order,
    unsigned short* __restrict__ xb)
{
  int j = blockIdx.x, k = blockIdx.y;
  int h = threadIdx.x;
  int base = k * BITEMS + j * MBS;
  float acc = 0.f, sp = 0.f;
  #pragma unroll
  for (int m = 0; m < MBS; m++) {
    int it = seq[base + m];
    if (it >= 0) {
      float p = prob[base + m];
      sp += p;
      acc += p * table[(size_t)(it + 1) * HD + h];
    }
  }
  float val = acc / (sp + 1e-10f);
  int dest = order[k * NBASK + j];
  xb[((size_t)k * NBASK + dest) * HD + h] = f2b(val);
}

// ---------------- input GEMM: gi = X(bf16) @ W(bf16)^T + bias --------------
// X [M=16384][256], W [768][256], Y [M][768] fp32
__global__ __launch_bounds__(256) void k_gemm(
    const unsigned short* __restrict__ X, const unsigned short* __restrict__ W,
    const float* __restrict__ bias, float* __restrict__ Y)
{
  int nblk = blockIdx.x;              // 0..11
  int mblk = blockIdx.y;              // 0..255
  int wv = threadIdx.x >> 6;
  int l = threadIdx.x & 63;
  int r = l & 15, g = l >> 4;
  int mbase = mblk * 64 + wv * 16;
  int nbase = nblk * 64;
  v4f acc[4];
  #pragma unroll
  for (int c = 0; c < 4; c++) {
    float bn = bias[nbase + c * 16 + r];
    acc[c] = (v4f){bn, bn, bn, bn};
  }
  const unsigned short* xrow = X + (size_t)(mbase + r) * HD;
  #pragma unroll
  for (int k0 = 0; k0 < HD; k0 += 32) {
    v8s a = *(const v8s*)(xrow + k0 + g * 8);
    #pragma unroll
    for (int c = 0; c < 4; c++) {
      const unsigned short* wrow = W + (size_t)(nbase + c * 16 + r) * HD;
      v8s b = *(const v8s*)(wrow + k0 + g * 8);
      acc[c] = __builtin_amdgcn_mfma_f32_16x16x32_bf16(a, b, acc[c], 0, 0, 0);
    }
  }
  #pragma unroll
  for (int c = 0; c < 4; c++) {
    int n = nbase + c * 16 + r;
    int mrow = mbase + g * 4;
    #pragma unroll
    for (int i = 0; i < 4; i++)
      Y[(size_t)(mrow + i) * G3 + n] = acc[c][i];
  }
}

// ---------------- fused 2-layer GRU recurrence -----------------------------
// 16 blocks x 1024 threads; block owns 16 users for all 64 steps.
// h kept as bf16 hi+lo pair (fp32-equivalent); weights bf16 hi+lo.
__device__ __forceinline__ void mm_phase(
    const unsigned short (*Ahi)[264], const unsigned short (*Alo)[264],
    const unsigned short* __restrict__ Bhi, const unsigned short* __restrict__ Blo,
    const float* __restrict__ bias, float (*dst)[772], int wv, int r, int g)
{
  #pragma unroll
  for (int tt = 0; tt < 3; tt++) {
    int gb = (wv * 3 + tt) * 16;
    float bn = bias[gb + r];
    v4f acc = (v4f){bn, bn, bn, bn};
    const unsigned short* whi = Bhi + (size_t)(gb + r) * HD;
    const unsigned short* wlo = Blo + (size_t)(gb + r) * HD;
    #pragma unroll
    for (int k0 = 0; k0 < HD; k0 += 32) {
      v8s ahi = *(const v8s*)(&Ahi[r][k0 + g * 8]);
      v8s alo = *(const v8s*)(&Alo[r][k0 + g * 8]);
      v8s bhi = *(const v8s*)(whi + k0 + g * 8);
      v8s blo = *(const v8s*)(wlo + k0 + g * 8);
      acc = __builtin_amdgcn_mfma_f32_16x16x32_bf16(ahi, bhi, acc, 0, 0, 0);
      acc = __builtin_amdgcn_mfma_f32_16x16x32_bf16(ahi, blo, acc, 0, 0, 0);
      acc = __builtin_amdgcn_mfma_f32_16x16x32_bf16(alo, bhi, acc, 0, 0, 0);
    }
    #pragma unroll
    for (int i = 0; i < 4; i++) dst[g * 4 + i][gb + r] = acc[i];
  }
}

__global__ __launch_bounds__(1024) void k_recur(
    const unsigned short* __restrict__ whh1hi, const unsigned short* __restrict__ whh1lo,
    const unsigned short* __restrict__ whh2hi, const unsigned short* __restrict__ whh2lo,
    const unsigned short* __restrict__ wih2hi, const unsigned short* __restrict__ wih2lo,
    const float* __restrict__ gi1,
    const float* __restrict__ bih2, const float* __restrict__ bhh1, const float* __restrict__ bhh2,
    const int* __restrict__ lengths, float* __restrict__ out)
{
  __shared__ unsigned short h1hi[16][264], h1lo[16][264], h2hi[16][264], h2lo[16][264];
  __shared__ float bufA[16][772], bufB[16][772];
  __shared__ int len_s[16];
  int tid = threadIdx.x;
  int wv = tid >> 6, l = tid & 63, r = l & 15, g = l >> 4;
  int ub = blockIdx.x * 16;
  for (int i = tid; i < 16 * 264; i += 1024) {
    int u = i / 264, c = i % 264;
    h1hi[u][c] = 0; h1lo[u][c] = 0; h2hi[u][c] = 0; h2lo[u][c] = 0;
  }
  if (tid < 16) len_s[tid] = lengths[ub + tid];
  __syncthreads();

  for (int t = 0; t < TT; t++) {
    // A: gh1 = h1 @ whh1^T + bhh1 -> bufA
    mm_phase(h1hi, h1lo, whh1hi, whh1lo, bhh1, bufA, wv, r, g);
    __syncthreads();
    // B: layer-1 gates
    #pragma unroll
    for (int p = 0; p < 4; p++) {
      int flat = p * 1024 + tid;
      int u = flat >> 8, j = flat & 255;
      const float* grow = gi1 + ((size_t)(ub + u) * TT + t) * G3;
      float ir = grow[j], iz = grow[256 + j], inn = grow[512 + j];
      float hr = bufA[u][j], hz = bufA[u][256 + j], hn = bufA[u][512 + j];
      float rr = 1.f / (1.f + __expf(-(ir + hr)));
      float zz = 1.f / (1.f + __expf(-(iz + hz)));
      float e  = __expf(2.f * (inn + rr * hn));
      float nn = 1.f - 2.f / (e + 1.f);
      float hold = b2f(h1hi[u][j]) + b2f(h1lo[u][j]);
      float hnew = (1.f - zz) * nn + zz * hold;
      unsigned short hi = f2b(hnew);
      h1hi[u][j] = hi; h1lo[u][j] = f2b(hnew - b2f(hi));
    }
    __syncthreads();
    // C: gi2 = h1 @ wih2^T + bih2 -> bufB ; D: gh2 = h2 @ whh2^T + bhh2 -> bufA
    mm_phase(h1hi, h1lo, wih2hi, wih2lo, bih2, bufB, wv, r, g);
    mm_phase(h2hi, h2lo, whh2hi, whh2lo, bhh2, bufA, wv, r, g);
    __syncthreads();
    // E: layer-2 gates + output at t == len-1
    #pragma unroll
    for (int p = 0; p < 4; p++) {
      int flat = p * 1024 + tid;
      int u = flat >> 8, j = flat & 255;
      float ir = bufB[u][j], iz = bufB[u][256 + j], inn = bufB[u][512 + j];
      float hr = bufA[u][j], hz = bufA[u][256 + j], hn = bufA[u][512 + j];
      float rr = 1.f / (1.f + __expf(-(ir + hr)));
      float zz = 1.f / (1.f + __expf(-(iz + hz)));
      float e  = __expf(2.f * (inn + rr * hn));
      float nn = 1.f - 2.f / (e + 1.f);
      float hold = b2f(h2hi[u][j]) + b2f(h2lo[u][j]);
      float hnew = (1.f - zz) * nn + zz * hold;
      unsigned short hi = f2b(hnew);
      h2hi[u][j] = hi; h2lo[u][j] = f2b(hnew - b2f(hi));
      if (t == len_s[u] - 1) out[(size_t)(ub + u) * HD + j] = hnew;
    }
    __syncthreads();
  }
}

extern "C" void kernel_launch(void* const* d_in, const int* in_sizes, int n_in,
                              void* d_out, int out_size, void* d_ws, size_t ws_size,
                              hipStream_t stream) {
  const float* prob  = (const float*)d_in[0];
  const int*   seq   = (const int*)d_in[1];
  // d_in[2] = uid (unused by the reference output)
  const float* table = (const float*)d_in[3];
  const float* wih   = (const float*)d_in[4];
  const float* whh   = (const float*)d_in[5];
  const float* bih   = (const float*)d_in[6];
  const float* bhh   = (const float*)d_in[7];
  float* out = (float*)d_out;

  char* ws = (char*)d_ws;
  unsigned short* xb  = (unsigned short*)(ws);                 // 8,388,608 B
  float* gi1          = (float*)(ws + 8388608);                // 50,331,648 B
  char* wsw           = ws + 58720256;
  const size_t WSZ = 393216;                                   // 768*256*2
  unsigned short* wih1b  = (unsigned short*)(wsw + 0 * WSZ);
  unsigned short* wih2hi = (unsigned short*)(wsw + 1 * WSZ);
  unsigned short* wih2lo = (unsigned short*)(wsw + 2 * WSZ);
  unsigned short* whh1hi = (unsigned short*)(wsw + 3 * WSZ);
  unsigned short* whh1lo = (unsigned short*)(wsw + 4 * WSZ);
  unsigned short* whh2hi = (unsigned short*)(wsw + 5 * WSZ);
  unsigned short* whh2lo = (unsigned short*)(wsw + 6 * WSZ);
  int* order   = (int*)(wsw + 7 * WSZ);
  int* lengths = order + KU * NBASK;

  k_convert<<<dim3(192, 4), 1024, 0, stream>>>(wih, whh, wih1b, wih2hi, wih2lo,
                                               whh1hi, whh1lo, whh2hi, whh2lo);
  k_order<<<dim3(KU), 64, 0, stream>>>(prob, seq, order, lengths);
  k_basket<<<dim3(NBASK, KU), 256, 0, stream>>>(prob, seq, table, order, xb);
  k_gemm<<<dim3(12, 256), 256, 0, stream>>>(xb, wih1b, bih, gi1);
  k_recur<<<dim3(16), 1024, 0, stream>>>(whh1hi, whh1lo, whh2hi, whh2lo,
                                         wih2hi, wih2lo, gi1,
                                         bih + G3, bhh, bhh + G3, lengths, out);
}

// Round 2
// 2275.401 us; speedup vs baseline: 1.9961x; 1.9961x over previous
//
#include <hip/hip_runtime.h>
#include <cstdint>

#define KU 256
#define NBASK 64
#define MBS 20
#define BITEMS 1280
#define HD 256
#define G3 768
#define TT 64

typedef short v8s __attribute__((ext_vector_type(8)));
typedef float v4f __attribute__((ext_vector_type(4)));

__device__ __forceinline__ unsigned short f2b(float f){
  uint32_t u = __float_as_uint(f);
  u += 0x7FFFu + ((u >> 16) & 1u);
  return (unsigned short)(u >> 16);
}
__device__ __forceinline__ float b2f(unsigned short s){
  return __uint_as_float(((uint32_t)s) << 16);
}

// ---------------- weight conversion: fp32 -> bf16 hi + residual lo ---------
__global__ __launch_bounds__(1024) void k_convert(
    const float* __restrict__ wih, const float* __restrict__ whh,
    unsigned short* __restrict__ wih1hi, unsigned short* __restrict__ wih1lo,
    unsigned short* __restrict__ wih2hi, unsigned short* __restrict__ wih2lo,
    unsigned short* __restrict__ whh1hi, unsigned short* __restrict__ whh1lo,
    unsigned short* __restrict__ whh2hi, unsigned short* __restrict__ whh2lo)
{
  int idx = blockIdx.x * 1024 + threadIdx.x;     // 0..196607
  int which = blockIdx.y;
  float v;
  if (which == 0)      v = wih[idx];
  else if (which == 1) v = wih[196608 + idx];
  else if (which == 2) v = whh[idx];
  else                 v = whh[196608 + idx];
  unsigned short hi = f2b(v);
  unsigned short lo = f2b(v - b2f(hi));
  if (which == 0)      { wih1hi[idx] = hi; wih1lo[idx] = lo; }
  else if (which == 1) { wih2hi[idx] = hi; wih2lo[idx] = lo; }
  else if (which == 2) { whh1hi[idx] = hi; whh1lo[idx] = lo; }
  else                 { whh2hi[idx] = hi; whh2lo[idx] = lo; }
}

// ---------------- per-user basket ordering (stable: valid first) -----------
__global__ __launch_bounds__(64) void k_order(
    const float* __restrict__ prob, const int* __restrict__ seq,
    int* __restrict__ order, int* __restrict__ lengths)
{
  int k = blockIdx.x, j = threadIdx.x;           // j = basket
  int base = k * BITEMS + j * MBS;
  float mx = 0.f;
  #pragma unroll
  for (int m = 0; m < MBS; m++) {
    int it = seq[base + m];
    float p = (it >= 0) ? prob[base + m] : 0.f;
    mx = fmaxf(mx, p);
  }
  bool valid = mx > 0.f;
  unsigned long long bal = __ballot(valid);
  int len = __popcll(bal);
  unsigned long long below = bal & ((1ull << j) - 1ull);
  int pos = valid ? __popcll(below) : (len + (j - __popcll(below)));
  order[k * NBASK + j] = pos;
  if (j == 0) lengths[k] = (len > 0) ? len : 1;
}

// ---------------- basket pooling -> ordered x (bf16 hi+lo) -----------------
__global__ __launch_bounds__(256) void k_basket(
    const float* __restrict__ prob, const int* __restrict__ seq,
    const float* __restrict__ table, const int* __restrict__ order,
    unsigned short* __restrict__ xbhi, unsigned short* __restrict__ xblo)
{
  int j = blockIdx.x, k = blockIdx.y;
  int h = threadIdx.x;
  int base = k * BITEMS + j * MBS;
  float acc = 0.f, sp = 0.f;
  #pragma unroll
  for (int m = 0; m < MBS; m++) {
    int it = seq[base + m];
    if (it >= 0) {
      float p = prob[base + m];
      sp += p;
      acc += p * table[(size_t)(it + 1) * HD + h];
    }
  }
  float val = acc / (sp + 1e-10f);
  int dest = order[k * NBASK + j];
  unsigned short hi = f2b(val);
  size_t o = ((size_t)k * NBASK + dest) * HD + h;
  xbhi[o] = hi;
  xblo[o] = f2b(val - b2f(hi));
}

// ---------------- 3-product split-bf16 GEMM: Y = X @ W^T + bias ------------
// X [16384][256] (hi,lo), W [768][256] (hi,lo), Y [16384][768] fp32
__global__ __launch_bounds__(256) void k_gemm3(
    const unsigned short* __restrict__ Xhi, const unsigned short* __restrict__ Xlo,
    const unsigned short* __restrict__ Whi, const unsigned short* __restrict__ Wlo,
    const float* __restrict__ bias, float* __restrict__ Y)
{
  int nblk = blockIdx.x;              // 0..11
  int mblk = blockIdx.y;              // 0..255
  int wv = threadIdx.x >> 6;
  int l = threadIdx.x & 63;
  int r = l & 15, g = l >> 4;
  int mbase = mblk * 64 + wv * 16;
  int nbase = nblk * 64;
  v4f acc[4];
  #pragma unroll
  for (int c = 0; c < 4; c++) {
    float bn = bias[nbase + c * 16 + r];
    acc[c] = (v4f){bn, bn, bn, bn};
  }
  const unsigned short* xh = Xhi + (size_t)(mbase + r) * HD;
  const unsigned short* xl = Xlo + (size_t)(mbase + r) * HD;
  #pragma unroll
  for (int k0 = 0; k0 < HD; k0 += 32) {
    v8s ahi = *(const v8s*)(xh + k0 + g * 8);
    v8s alo = *(const v8s*)(xl + k0 + g * 8);
    #pragma unroll
    for (int c = 0; c < 4; c++) {
      size_t wo = (size_t)(nbase + c * 16 + r) * HD + k0 + g * 8;
      v8s bhi = *(const v8s*)(Whi + wo);
      v8s blo = *(const v8s*)(Wlo + wo);
      acc[c] = __builtin_amdgcn_mfma_f32_16x16x32_bf16(ahi, bhi, acc[c], 0, 0, 0);
      acc[c] = __builtin_amdgcn_mfma_f32_16x16x32_bf16(alo, bhi, acc[c], 0, 0, 0);
      acc[c] = __builtin_amdgcn_mfma_f32_16x16x32_bf16(ahi, blo, acc[c], 0, 0, 0);
    }
  }
  #pragma unroll
  for (int c = 0; c < 4; c++) {
    int n = nbase + c * 16 + r;
    int mrow = mbase + g * 4;
    #pragma unroll
    for (int i = 0; i < 4; i++)
      Y[(size_t)(mrow + i) * G3 + n] = acc[c][i];
  }
}

// ---------------- single-layer GRU recurrence, weights register-resident ---
// 16 blocks x 512 threads (8 waves). Block owns users [16b,16b+16).
// whh-hi: 6 tiles x 8 kslices per wave in VGPRs. whh-lo streamed from L2.
// h kept hi+lo in LDS, 16B-slot XOR swizzle -> conflict-free ds_read_b128.
// MODE 0: publish h(t) sequence (hi+lo).  MODE 1: write out at t==len-1.
template<int MODE>
__global__ __launch_bounds__(512) void k_recur(
    const unsigned short* __restrict__ whi_g, const unsigned short* __restrict__ wlo_g,
    const float* __restrict__ gi, const float* __restrict__ bhh,
    const int* __restrict__ lengths,
    unsigned short* __restrict__ hseq_hi, unsigned short* __restrict__ hseq_lo,
    float* __restrict__ out)
{
  __shared__ unsigned short h_hi[16][256], h_lo[16][256];
  __shared__ float bufA[16 * 32 * 25];     // [user][j8] blocks of 24 floats +1 pad
  __shared__ int len_s[16];
  int tid = threadIdx.x;
  int wv = tid >> 6, l = tid & 63, r = l & 15, g = l >> 4;
  int ub = blockIdx.x * 16;
  int u = tid >> 5, j8 = tid & 31;         // gate-phase coords

  for (int idx = tid; idx < 4096; idx += 512) {
    ((unsigned short*)h_hi)[idx] = 0;
    ((unsigned short*)h_lo)[idx] = 0;
  }
  if (MODE == 1 && tid < 16) len_s[tid] = lengths[ub + tid];

  // preload whh-hi fragments + bias (persistent registers)
  v8s whi[6][8];
  float bias_r[6];
  int wrow[6];
  #pragma unroll
  for (int tt = 0; tt < 6; tt++) {
    int R = (wv * 6 + tt) * 16 + r;
    wrow[tt] = R * 256;
    bias_r[tt] = bhh[R];
    #pragma unroll
    for (int kk = 0; kk < 8; kk++)
      whi[tt][kk] = *(const v8s*)&whi_g[R * 256 + kk * 32 + g * 8];
  }
  __syncthreads();

  const float* gi_u = gi + ((size_t)(ub + u) * TT) * G3 + j8 * 8;

  for (int t = 0; t < TT; t++) {
    // ---- MM: gh = h @ whh^T + bhh ----
    v4f acc[6];
    #pragma unroll
    for (int tt = 0; tt < 6; tt++)
      acc[tt] = (v4f){bias_r[tt], bias_r[tt], bias_r[tt], bias_r[tt]};
    #pragma unroll
    for (int kk = 0; kk < 8; kk++) {
      int slot = ((kk * 4 + g) ^ (r & 7)) * 8;
      v8s ahi = *(const v8s*)&h_hi[r][slot];
      v8s alo = *(const v8s*)&h_lo[r][slot];
      #pragma unroll
      for (int tt = 0; tt < 6; tt++) {
        v8s blo = *(const v8s*)&wlo_g[wrow[tt] + kk * 32 + g * 8];
        acc[tt] = __builtin_amdgcn_mfma_f32_16x16x32_bf16(ahi, whi[tt][kk], acc[tt], 0, 0, 0);
        acc[tt] = __builtin_amdgcn_mfma_f32_16x16x32_bf16(alo, whi[tt][kk], acc[tt], 0, 0, 0);
        acc[tt] = __builtin_amdgcn_mfma_f32_16x16x32_bf16(ahi, blo,         acc[tt], 0, 0, 0);
      }
    }
    // ---- prefetch gi(t) into registers (hides HBM latency under scatter+barrier)
    const float* grow = gi_u + (size_t)t * G3;
    v4f gi_reg[6];
    #pragma unroll
    for (int s = 0; s < 3; s++) {
      gi_reg[s * 2]     = *(const v4f*)(grow + s * 256);
      gi_reg[s * 2 + 1] = *(const v4f*)(grow + s * 256 + 4);
    }
    // ---- scatter gh to bufA ----
    #pragma unroll
    for (int tt = 0; tt < 6; tt++) {
      int tau = wv * 6 + tt;
      int off = ((tau & 15) * 2 + (r >> 3)) * 25 + (tau >> 4) * 8 + (r & 7);
      #pragma unroll
      for (int i = 0; i < 4; i++)
        bufA[(g * 4 + i) * 800 + off] = acc[tt][i];
    }
    __syncthreads();
    // ---- gates ----
    int bb = (u * 32 + j8) * 25;
    int slot8 = (j8 ^ (u & 7)) * 8;
    float hnew_v[8];
    #pragma unroll
    for (int i = 0; i < 8; i++) {
      float ir  = gi_reg[0][i & 3], iz = gi_reg[2][i & 3], inn = gi_reg[4][i & 3];
      if (i >= 4) { ir = gi_reg[1][i & 3]; iz = gi_reg[3][i & 3]; inn = gi_reg[5][i & 3]; }
      float hr = bufA[bb + i], hz = bufA[bb + 8 + i], hn = bufA[bb + 16 + i];
      float rr = 1.f / (1.f + __expf(-(ir + hr)));
      float zz = 1.f / (1.f + __expf(-(iz + hz)));
      float e  = __expf(2.f * (inn + rr * hn));
      float nn = 1.f - 2.f / (e + 1.f);
      float hold = b2f(h_hi[u][slot8 + i]) + b2f(h_lo[u][slot8 + i]);
      float hnew = (1.f - zz) * nn + zz * hold;
      hnew_v[i] = hnew;
      unsigned short hi_ = f2b(hnew);
      h_hi[u][slot8 + i] = hi_;
      h_lo[u][slot8 + i] = f2b(hnew - b2f(hi_));
    }
    if (MODE == 0) {
      size_t o = ((size_t)(ub + u) * TT + t) * HD + j8 * 8;
      #pragma unroll
      for (int i = 0; i < 8; i++) {
        hseq_hi[o + i] = h_hi[u][slot8 + i];
        hseq_lo[o + i] = h_lo[u][slot8 + i];
      }
    } else {
      if (t == len_s[u] - 1) {
        #pragma unroll
        for (int i = 0; i < 8; i++)
          out[(size_t)(ub + u) * HD + j8 * 8 + i] = hnew_v[i];
      }
    }
    __syncthreads();
  }
}

extern "C" void kernel_launch(void* const* d_in, const int* in_sizes, int n_in,
                              void* d_out, int out_size, void* d_ws, size_t ws_size,
                              hipStream_t stream) {
  const float* prob  = (const float*)d_in[0];
  const int*   seq   = (const int*)d_in[1];
  // d_in[2] = uid (unused by the reference output)
  const float* table = (const float*)d_in[3];
  const float* wih   = (const float*)d_in[4];
  const float* whh   = (const float*)d_in[5];
  const float* bih   = (const float*)d_in[6];
  const float* bhh   = (const float*)d_in[7];
  float* out = (float*)d_out;

  char* ws = (char*)d_ws;
  float* gi            = (float*)ws;                          // 50,331,648 B (gi1, reused as gi2)
  unsigned short* xbhi = (unsigned short*)(ws + 50331648);    // 8 MB
  unsigned short* xblo = (unsigned short*)(ws + 58720256);    // 8 MB
  unsigned short* h1hi = xbhi;   // overlay: xb dead after gemm1, h1 born in recur1
  unsigned short* h1lo = xblo;
  char* wsw = ws + 67108864;
  const size_t WSZ = 393216;                                  // 768*256*2 B
  unsigned short* wih1hi = (unsigned short*)(wsw + 0 * WSZ);
  unsigned short* wih1lo = (unsigned short*)(wsw + 1 * WSZ);
  unsigned short* wih2hi = (unsigned short*)(wsw + 2 * WSZ);
  unsigned short* wih2lo = (unsigned short*)(wsw + 3 * WSZ);
  unsigned short* whh1hi = (unsigned short*)(wsw + 4 * WSZ);
  unsigned short* whh1lo = (unsigned short*)(wsw + 5 * WSZ);
  unsigned short* whh2hi = (unsigned short*)(wsw + 6 * WSZ);
  unsigned short* whh2lo = (unsigned short*)(wsw + 7 * WSZ);
  int* order   = (int*)(wsw + 8 * WSZ);
  int* lengths = order + KU * NBASK;

  k_convert<<<dim3(192, 4), 1024, 0, stream>>>(wih, whh,
      wih1hi, wih1lo, wih2hi, wih2lo, whh1hi, whh1lo, whh2hi, whh2lo);
  k_order<<<dim3(KU), 64, 0, stream>>>(prob, seq, order, lengths);
  k_basket<<<dim3(NBASK, KU), 256, 0, stream>>>(prob, seq, table, order, xbhi, xblo);
  // gi1 = x @ wih1^T + bih1
  k_gemm3<<<dim3(12, 256), 256, 0, stream>>>(xbhi, xblo, wih1hi, wih1lo, bih, gi);
  // layer-1 recurrence -> h1 sequence
  k_recur<0><<<dim3(16), 512, 0, stream>>>(whh1hi, whh1lo, gi, bhh,
                                           nullptr, h1hi, h1lo, nullptr);
  // gi2 = h1 @ wih2^T + bih2  (overwrites gi buffer)
  k_gemm3<<<dim3(12, 256), 256, 0, stream>>>(h1hi, h1lo, wih2hi, wih2lo, bih + G3, gi);
  // layer-2 recurrence -> output at t == len-1
  k_recur<1><<<dim3(16), 512, 0, stream>>>(whh2hi, whh2lo, gi, bhh + G3,
                                           lengths, nullptr, nullptr, out);
}

// Round 3
// 2264.109 us; speedup vs baseline: 2.0060x; 1.0050x over previous
//
#include <hip/hip_runtime.h>
#include <cstdint>

#define KU 256
#define NBASK 64
#define MBS 20
#define BITEMS 1280
#define HD 256
#define G3 768
#define TT 64

typedef short v8s __attribute__((ext_vector_type(8)));
typedef float v4f __attribute__((ext_vector_type(4)));

__device__ __forceinline__ unsigned short f2b(float f){
  uint32_t u = __float_as_uint(f);
  u += 0x7FFFu + ((u >> 16) & 1u);
  return (unsigned short)(u >> 16);
}
__device__ __forceinline__ float b2f(unsigned short s){
  return __uint_as_float(((uint32_t)s) << 16);
}
__device__ __forceinline__ void async_copy16(const float* g, float* l){
  __builtin_amdgcn_global_load_lds(
      (const __attribute__((address_space(1))) unsigned int*)g,
      (__attribute__((address_space(3))) unsigned int*)l, 16, 0, 0);
}

// ---------------- weight conversion: fp32 -> bf16 hi + residual lo ---------
__global__ __launch_bounds__(1024) void k_convert(
    const float* __restrict__ wih, const float* __restrict__ whh,
    unsigned short* __restrict__ wih1hi, unsigned short* __restrict__ wih1lo,
    unsigned short* __restrict__ wih2hi, unsigned short* __restrict__ wih2lo,
    unsigned short* __restrict__ whh1hi, unsigned short* __restrict__ whh1lo,
    unsigned short* __restrict__ whh2hi, unsigned short* __restrict__ whh2lo)
{
  int idx = blockIdx.x * 1024 + threadIdx.x;     // 0..196607
  int which = blockIdx.y;
  float v;
  if (which == 0)      v = wih[idx];
  else if (which == 1) v = wih[196608 + idx];
  else if (which == 2) v = whh[idx];
  else                 v = whh[196608 + idx];
  unsigned short hi = f2b(v);
  unsigned short lo = f2b(v - b2f(hi));
  if (which == 0)      { wih1hi[idx] = hi; wih1lo[idx] = lo; }
  else if (which == 1) { wih2hi[idx] = hi; wih2lo[idx] = lo; }
  else if (which == 2) { whh1hi[idx] = hi; whh1lo[idx] = lo; }
  else                 { whh2hi[idx] = hi; whh2lo[idx] = lo; }
}

// ---------------- per-user basket ordering (stable: valid first) -----------
__global__ __launch_bounds__(64) void k_order(
    const float* __restrict__ prob, const int* __restrict__ seq,
    int* __restrict__ order, int* __restrict__ lengths)
{
  int k = blockIdx.x, j = threadIdx.x;           // j = basket
  int base = k * BITEMS + j * MBS;
  float mx = 0.f;
  #pragma unroll
  for (int m = 0; m < MBS; m++) {
    int it = seq[base + m];
    float p = (it >= 0) ? prob[base + m] : 0.f;
    mx = fmaxf(mx, p);
  }
  bool valid = mx > 0.f;
  unsigned long long bal = __ballot(valid);
  int len = __popcll(bal);
  unsigned long long below = bal & ((1ull << j) - 1ull);
  int pos = valid ? __popcll(below) : (len + (j - __popcll(below)));
  order[k * NBASK + j] = pos;
  if (j == 0) lengths[k] = (len > 0) ? len : 1;
}

// ---------------- basket pooling -> ordered x (bf16 hi+lo) -----------------
__global__ __launch_bounds__(256) void k_basket(
    const float* __restrict__ prob, const int* __restrict__ seq,
    const float* __restrict__ table, const int* __restrict__ order,
    unsigned short* __restrict__ xbhi, unsigned short* __restrict__ xblo)
{
  int j = blockIdx.x, k = blockIdx.y;
  int h = threadIdx.x;
  int base = k * BITEMS + j * MBS;
  float acc = 0.f, sp = 0.f;
  #pragma unroll
  for (int m = 0; m < MBS; m++) {
    int it = seq[base + m];
    if (it >= 0) {
      float p = prob[base + m];
      sp += p;
      acc += p * table[(size_t)(it + 1) * HD + h];
    }
  }
  float val = acc / (sp + 1e-10f);
  int dest = order[k * NBASK + j];
  unsigned short hi = f2b(val);
  size_t o = ((size_t)k * NBASK + dest) * HD + h;
  xbhi[o] = hi;
  xblo[o] = f2b(val - b2f(hi));
}

// ---------------- 3-product split-bf16 GEMM: Y = X @ W^T + bias ------------
// X [16384][256] (hi,lo), W [768][256] (hi,lo), Y [16384][768] fp32
__global__ __launch_bounds__(256) void k_gemm3(
    const unsigned short* __restrict__ Xhi, const unsigned short* __restrict__ Xlo,
    const unsigned short* __restrict__ Whi, const unsigned short* __restrict__ Wlo,
    const float* __restrict__ bias, float* __restrict__ Y)
{
  int nblk = blockIdx.x;              // 0..11
  int mblk = blockIdx.y;              // 0..255
  int wv = threadIdx.x >> 6;
  int l = threadIdx.x & 63;
  int r = l & 15, g = l >> 4;
  int mbase = mblk * 64 + wv * 16;
  int nbase = nblk * 64;
  v4f acc[4];
  #pragma unroll
  for (int c = 0; c < 4; c++) {
    float bn = bias[nbase + c * 16 + r];
    acc[c] = (v4f){bn, bn, bn, bn};
  }
  const unsigned short* xh = Xhi + (size_t)(mbase + r) * HD;
  const unsigned short* xl = Xlo + (size_t)(mbase + r) * HD;
  #pragma unroll
  for (int k0 = 0; k0 < HD; k0 += 32) {
    v8s ahi = *(const v8s*)(xh + k0 + g * 8);
    v8s alo = *(const v8s*)(xl + k0 + g * 8);
    #pragma unroll
    for (int c = 0; c < 4; c++) {
      size_t wo = (size_t)(nbase + c * 16 + r) * HD + k0 + g * 8;
      v8s bhi = *(const v8s*)(Whi + wo);
      v8s blo = *(const v8s*)(Wlo + wo);
      acc[c] = __builtin_amdgcn_mfma_f32_16x16x32_bf16(ahi, bhi, acc[c], 0, 0, 0);
      acc[c] = __builtin_amdgcn_mfma_f32_16x16x32_bf16(alo, bhi, acc[c], 0, 0, 0);
      acc[c] = __builtin_amdgcn_mfma_f32_16x16x32_bf16(ahi, blo, acc[c], 0, 0, 0);
    }
  }
  #pragma unroll
  for (int c = 0; c < 4; c++) {
    int n = nbase + c * 16 + r;
    int mrow = mbase + g * 4;
    #pragma unroll
    for (int i = 0; i < 4; i++)
      Y[(size_t)(mrow + i) * G3 + n] = acc[c][i];
  }
}

// ---------------- single-layer GRU recurrence, weights register-resident ---
// 16 blocks x 512 threads (8 waves, 2/SIMD -> 256 VGPR budget).
// whh-hi: 6 tiles x 8 kslices per wave in VGPRs (192). whh-lo streamed (L2).
// gi(t) staged to LDS via global_load_lds (frees 24 VGPRs).
// MODE 0: publish h(t) sequence (hi+lo, vectorized). MODE 1: out at len-1.
template<int MODE>
__global__ __launch_bounds__(512, 2) void k_recur(
    const unsigned short* __restrict__ whi_g, const unsigned short* __restrict__ wlo_g,
    const float* __restrict__ gi, const float* __restrict__ bhh,
    const int* __restrict__ lengths,
    unsigned short* __restrict__ hseq_hi, unsigned short* __restrict__ hseq_lo,
    float* __restrict__ out)
{
  __shared__ unsigned short h_hi[16][256], h_lo[16][256];
  __shared__ float bufA[16 * 32 * 25];     // gh scatter: [user][j8] 24 floats +1 pad
  __shared__ float gi_lds[16][768];
  __shared__ int len_s[16];
  int tid = threadIdx.x;
  int wv = tid >> 6, l = tid & 63, r = l & 15, g = l >> 4;
  int ub = blockIdx.x * 16;
  int u = tid >> 5, j8 = tid & 31;         // gate-phase coords

  for (int idx = tid; idx < 4096; idx += 512) {
    ((unsigned short*)h_hi)[idx] = 0;
    ((unsigned short*)h_lo)[idx] = 0;
  }
  if (MODE == 1 && tid < 16) len_s[tid] = lengths[ub + tid];

  // preload whh-hi fragments + bias (persistent registers)
  v8s whi[6][8];
  float bias_r[6];
  int wrow[6];
  #pragma unroll
  for (int tt = 0; tt < 6; tt++) {
    int R = (wv * 6 + tt) * 16 + r;
    wrow[tt] = R * 256;
    bias_r[tt] = bhh[R];
    #pragma unroll
    for (int kk = 0; kk < 8; kk++)
      whi[tt][kk] = *(const v8s*)&whi_g[R * 256 + kk * 32 + g * 8];
  }
  __syncthreads();

  for (int t = 0; t < TT; t++) {
    // ---- async-stage gi(t) into LDS (overlaps with MFMA phase) ----
    {
      int u0 = wv * 2;
      #pragma unroll
      for (int c = 0; c < 6; c++) {
        int uu = u0 + (c >= 3), ch = (c >= 3) ? (c - 3) : c;
        const float* gsrc = gi + ((size_t)(ub + uu) * TT + t) * G3 + ch * 256 + l * 4;
        async_copy16(gsrc, &gi_lds[uu][ch * 256]);
      }
    }
    // ---- MM: gh = h @ whh^T + bhh ----
    v4f acc[6];
    #pragma unroll
    for (int tt = 0; tt < 6; tt++)
      acc[tt] = (v4f){bias_r[tt], bias_r[tt], bias_r[tt], bias_r[tt]};
    #pragma unroll
    for (int kk = 0; kk < 8; kk++) {
      int slot = ((kk * 4 + g) ^ (r & 7)) * 8;
      v8s ahi = *(const v8s*)&h_hi[r][slot];
      v8s alo = *(const v8s*)&h_lo[r][slot];
      #pragma unroll
      for (int tt = 0; tt < 6; tt++) {
        v8s blo = *(const v8s*)&wlo_g[wrow[tt] + kk * 32 + g * 8];
        acc[tt] = __builtin_amdgcn_mfma_f32_16x16x32_bf16(ahi, whi[tt][kk], acc[tt], 0, 0, 0);
        acc[tt] = __builtin_amdgcn_mfma_f32_16x16x32_bf16(alo, whi[tt][kk], acc[tt], 0, 0, 0);
        acc[tt] = __builtin_amdgcn_mfma_f32_16x16x32_bf16(ahi, blo,         acc[tt], 0, 0, 0);
      }
    }
    // ---- scatter gh to bufA ----
    #pragma unroll
    for (int tt = 0; tt < 6; tt++) {
      int tau = wv * 6 + tt;
      int off = ((tau & 15) * 2 + (r >> 3)) * 25 + (tau >> 4) * 8 + (r & 7);
      #pragma unroll
      for (int i = 0; i < 4; i++)
        bufA[(g * 4 + i) * 800 + off] = acc[tt][i];
    }
    __syncthreads();                     // also drains gi_lds async loads
    // ---- gates ----
    int bb = (u * 32 + j8) * 25;
    int slot8 = (j8 ^ (u & 7)) * 8;
    const float* gu = &gi_lds[u][j8 * 8];
    v4f g0 = *(const v4f*)(gu);
    v4f g1 = *(const v4f*)(gu + 4);
    v4f g2 = *(const v4f*)(gu + 256);
    v4f g3 = *(const v4f*)(gu + 260);
    v4f g4 = *(const v4f*)(gu + 512);
    v4f g5 = *(const v4f*)(gu + 516);
    float hnew_v[8];
    v8s hi_vec, lo_vec;
    #pragma unroll
    for (int i = 0; i < 8; i++) {
      float ir  = (i < 4) ? g0[i & 3] : g1[i & 3];
      float iz  = (i < 4) ? g2[i & 3] : g3[i & 3];
      float inn = (i < 4) ? g4[i & 3] : g5[i & 3];
      float hr = bufA[bb + i], hz = bufA[bb + 8 + i], hn = bufA[bb + 16 + i];
      float rr = 1.f / (1.f + __expf(-(ir + hr)));
      float zz = 1.f / (1.f + __expf(-(iz + hz)));
      float e  = __expf(2.f * (inn + rr * hn));
      float nn = 1.f - 2.f / (e + 1.f);
      float hold = b2f(h_hi[u][slot8 + i]) + b2f(h_lo[u][slot8 + i]);
      float hnew = (1.f - zz) * nn + zz * hold;
      hnew_v[i] = hnew;
      unsigned short hi_ = f2b(hnew);
      unsigned short lo_ = f2b(hnew - b2f(hi_));
      h_hi[u][slot8 + i] = hi_;
      h_lo[u][slot8 + i] = lo_;
      hi_vec[i] = (short)hi_;
      lo_vec[i] = (short)lo_;
    }
    if (MODE == 0) {
      size_t o = ((size_t)(ub + u) * TT + t) * HD + j8 * 8;
      *(v8s*)&hseq_hi[o] = hi_vec;
      *(v8s*)&hseq_lo[o] = lo_vec;
    } else {
      if (t == len_s[u] - 1) {
        float* op = out + (size_t)(ub + u) * HD + j8 * 8;
        #pragma unroll
        for (int i = 0; i < 8; i++) op[i] = hnew_v[i];
      }
    }
    __syncthreads();
  }
}

extern "C" void kernel_launch(void* const* d_in, const int* in_sizes, int n_in,
                              void* d_out, int out_size, void* d_ws, size_t ws_size,
                              hipStream_t stream) {
  const float* prob  = (const float*)d_in[0];
  const int*   seq   = (const int*)d_in[1];
  // d_in[2] = uid (unused by the reference output)
  const float* table = (const float*)d_in[3];
  const float* wih   = (const float*)d_in[4];
  const float* whh   = (const float*)d_in[5];
  const float* bih   = (const float*)d_in[6];
  const float* bhh   = (const float*)d_in[7];
  float* out = (float*)d_out;

  char* ws = (char*)d_ws;
  float* gi            = (float*)ws;                          // 50,331,648 B (gi1, reused as gi2)
  unsigned short* xbhi = (unsigned short*)(ws + 50331648);    // 8 MB
  unsigned short* xblo = (unsigned short*)(ws + 58720256);    // 8 MB
  unsigned short* h1hi = xbhi;   // overlay: xb dead after gemm1, h1 born in recur1
  unsigned short* h1lo = xblo;
  char* wsw = ws + 67108864;
  const size_t WSZ = 393216;                                  // 768*256*2 B
  unsigned short* wih1hi = (unsigned short*)(wsw + 0 * WSZ);
  unsigned short* wih1lo = (unsigned short*)(wsw + 1 * WSZ);
  unsigned short* wih2hi = (unsigned short*)(wsw + 2 * WSZ);
  unsigned short* wih2lo = (unsigned short*)(wsw + 3 * WSZ);
  unsigned short* whh1hi = (unsigned short*)(wsw + 4 * WSZ);
  unsigned short* whh1lo = (unsigned short*)(wsw + 5 * WSZ);
  unsigned short* whh2hi = (unsigned short*)(wsw + 6 * WSZ);
  unsigned short* whh2lo = (unsigned short*)(wsw + 7 * WSZ);
  int* order   = (int*)(wsw + 8 * WSZ);
  int* lengths = order + KU * NBASK;

  k_convert<<<dim3(192, 4), 1024, 0, stream>>>(wih, whh,
      wih1hi, wih1lo, wih2hi, wih2lo, whh1hi, whh1lo, whh2hi, whh2lo);
  k_order<<<dim3(KU), 64, 0, stream>>>(prob, seq, order, lengths);
  k_basket<<<dim3(NBASK, KU), 256, 0, stream>>>(prob, seq, table, order, xbhi, xblo);
  // gi1 = x @ wih1^T + bih1
  k_gemm3<<<dim3(12, 256), 256, 0, stream>>>(xbhi, xblo, wih1hi, wih1lo, bih, gi);
  // layer-1 recurrence -> h1 sequence
  k_recur<0><<<dim3(16), 512, 0, stream>>>(whh1hi, whh1lo, gi, bhh,
                                           nullptr, h1hi, h1lo, nullptr);
  // gi2 = h1 @ wih2^T + bih2  (overwrites gi buffer)
  k_gemm3<<<dim3(12, 256), 256, 0, stream>>>(h1hi, h1lo, wih2hi, wih2lo, bih + G3, gi);
  // layer-2 recurrence -> output at t == len-1
  k_recur<1><<<dim3(16), 512, 0, stream>>>(whh2hi, whh2lo, gi, bhh + G3,
                                           lengths, nullptr, nullptr, out);
}

// Round 4
// 2170.897 us; speedup vs baseline: 2.0921x; 1.0429x over previous
//
#include <hip/hip_runtime.h>
#include <cstdint>

#define KU 256
#define NBASK 64
#define MBS 20
#define BITEMS 1280
#define HD 256
#define G3 768
#define TT 64

typedef short v8s __attribute__((ext_vector_type(8)));
typedef float v4f __attribute__((ext_vector_type(4)));

__device__ __forceinline__ unsigned short f2b(float f){
  uint32_t u = __float_as_uint(f);
  u += 0x7FFFu + ((u >> 16) & 1u);
  return (unsigned short)(u >> 16);
}
__device__ __forceinline__ float b2f(unsigned short s){
  return __uint_as_float(((uint32_t)s) << 16);
}
__device__ __forceinline__ void async_copy16(const float* g, float* l){
  __builtin_amdgcn_global_load_lds(
      (const __attribute__((address_space(1))) unsigned int*)g,
      (__attribute__((address_space(3))) unsigned int*)l, 16, 0, 0);
}

// ---------------- weight conversion: fp32 -> bf16 hi + residual lo ---------
__global__ __launch_bounds__(1024) void k_convert(
    const float* __restrict__ wih, const float* __restrict__ whh,
    unsigned short* __restrict__ wih1hi, unsigned short* __restrict__ wih1lo,
    unsigned short* __restrict__ wih2hi, unsigned short* __restrict__ wih2lo,
    unsigned short* __restrict__ whh1hi, unsigned short* __restrict__ whh1lo,
    unsigned short* __restrict__ whh2hi, unsigned short* __restrict__ whh2lo)
{
  int idx = blockIdx.x * 1024 + threadIdx.x;     // 0..196607
  int which = blockIdx.y;
  float v;
  if (which == 0)      v = wih[idx];
  else if (which == 1) v = wih[196608 + idx];
  else if (which == 2) v = whh[idx];
  else                 v = whh[196608 + idx];
  unsigned short hi = f2b(v);
  unsigned short lo = f2b(v - b2f(hi));
  if (which == 0)      { wih1hi[idx] = hi; wih1lo[idx] = lo; }
  else if (which == 1) { wih2hi[idx] = hi; wih2lo[idx] = lo; }
  else if (which == 2) { whh1hi[idx] = hi; whh1lo[idx] = lo; }
  else                 { whh2hi[idx] = hi; whh2lo[idx] = lo; }
}

// ---------------- per-user basket ordering (stable: valid first) -----------
__global__ __launch_bounds__(64) void k_order(
    const float* __restrict__ prob, const int* __restrict__ seq,
    int* __restrict__ order, int* __restrict__ lengths)
{
  int k = blockIdx.x, j = threadIdx.x;           // j = basket
  int base = k * BITEMS + j * MBS;
  float mx = 0.f;
  #pragma unroll
  for (int m = 0; m < MBS; m++) {
    int it = seq[base + m];
    float p = (it >= 0) ? prob[base + m] : 0.f;
    mx = fmaxf(mx, p);
  }
  bool valid = mx > 0.f;
  unsigned long long bal = __ballot(valid);
  int len = __popcll(bal);
  unsigned long long below = bal & ((1ull << j) - 1ull);
  int pos = valid ? __popcll(below) : (len + (j - __popcll(below)));
  order[k * NBASK + j] = pos;
  if (j == 0) lengths[k] = (len > 0) ? len : 1;
}

// ---------------- basket pooling -> ordered x (bf16 hi+lo) -----------------
__global__ __launch_bounds__(256) void k_basket(
    const float* __restrict__ prob, const int* __restrict__ seq,
    const float* __restrict__ table, const int* __restrict__ order,
    unsigned short* __restrict__ xbhi, unsigned short* __restrict__ xblo)
{
  int j = blockIdx.x, k = blockIdx.y;
  int h = threadIdx.x;
  int base = k * BITEMS + j * MBS;
  float acc = 0.f, sp = 0.f;
  #pragma unroll
  for (int m = 0; m < MBS; m++) {
    int it = seq[base + m];
    if (it >= 0) {
      float p = prob[base + m];
      sp += p;
      acc += p * table[(size_t)(it + 1) * HD + h];
    }
  }
  float val = acc / (sp + 1e-10f);
  int dest = order[k * NBASK + j];
  unsigned short hi = f2b(val);
  size_t o = ((size_t)k * NBASK + dest) * HD + h;
  xbhi[o] = hi;
  xblo[o] = f2b(val - b2f(hi));
}

// ---------------- 3-product split-bf16 GEMM: Y = X @ W^T + bias ------------
// X [16384][256] (hi,lo), W [768][256] (hi,lo), Y [16384][768] fp32
__global__ __launch_bounds__(256) void k_gemm3(
    const unsigned short* __restrict__ Xhi, const unsigned short* __restrict__ Xlo,
    const unsigned short* __restrict__ Whi, const unsigned short* __restrict__ Wlo,
    const float* __restrict__ bias, float* __restrict__ Y)
{
  int nblk = blockIdx.x;              // 0..11
  int mblk = blockIdx.y;              // 0..255
  int wv = threadIdx.x >> 6;
  int l = threadIdx.x & 63;
  int r = l & 15, g = l >> 4;
  int mbase = mblk * 64 + wv * 16;
  int nbase = nblk * 64;
  v4f acc[4];
  #pragma unroll
  for (int c = 0; c < 4; c++) {
    float bn = bias[nbase + c * 16 + r];
    acc[c] = (v4f){bn, bn, bn, bn};
  }
  const unsigned short* xh = Xhi + (size_t)(mbase + r) * HD;
  const unsigned short* xl = Xlo + (size_t)(mbase + r) * HD;
  #pragma unroll
  for (int k0 = 0; k0 < HD; k0 += 32) {
    v8s ahi = *(const v8s*)(xh + k0 + g * 8);
    v8s alo = *(const v8s*)(xl + k0 + g * 8);
    #pragma unroll
    for (int c = 0; c < 4; c++) {
      size_t wo = (size_t)(nbase + c * 16 + r) * HD + k0 + g * 8;
      v8s bhi = *(const v8s*)(Whi + wo);
      v8s blo = *(const v8s*)(Wlo + wo);
      acc[c] = __builtin_amdgcn_mfma_f32_16x16x32_bf16(ahi, bhi, acc[c], 0, 0, 0);
      acc[c] = __builtin_amdgcn_mfma_f32_16x16x32_bf16(alo, bhi, acc[c], 0, 0, 0);
      acc[c] = __builtin_amdgcn_mfma_f32_16x16x32_bf16(ahi, blo, acc[c], 0, 0, 0);
    }
  }
  #pragma unroll
  for (int c = 0; c < 4; c++) {
    int n = nbase + c * 16 + r;
    int mrow = mbase + g * 4;
    #pragma unroll
    for (int i = 0; i < 4; i++)
      Y[(size_t)(mrow + i) * G3 + n] = acc[c][i];
  }
}

// ---------------- single-layer GRU recurrence, weights register-resident ---
// 16 blocks x 512 threads (8 waves). amdgpu_waves_per_eu(2,2) -> 256-VGPR cap.
// whh-hi: 6 tiles x 8 kslices per wave in VGPRs (192). whh-lo streamed (L2).
// gi(t) staged to LDS via global_load_lds. bias added in gates phase (LDS).
// MODE 0: publish h(t) sequence (hi+lo). MODE 1: out at t==len-1.
template<int MODE>
__global__ __launch_bounds__(512) __attribute__((amdgpu_waves_per_eu(2, 2)))
void k_recur(
    const unsigned short* __restrict__ whi_g, const unsigned short* __restrict__ wlo_g,
    const float* __restrict__ gi, const float* __restrict__ bhh,
    const int* __restrict__ lengths,
    unsigned short* __restrict__ hseq_hi, unsigned short* __restrict__ hseq_lo,
    float* __restrict__ out)
{
  __shared__ unsigned short h_hi[16][256], h_lo[16][256];
  __shared__ float bufA[16 * 32 * 25];     // gh scatter: [user][j8] 24 floats +1 pad
  __shared__ float gi_lds[16][768];
  __shared__ float bhh_s[768];
  __shared__ int len_s[16];
  int tid = threadIdx.x;
  int wv = tid >> 6, l = tid & 63, r = l & 15, g = l >> 4;
  int ub = blockIdx.x * 16;
  int u = tid >> 5, j8 = tid & 31;         // gate-phase coords

  for (int idx = tid; idx < 4096; idx += 512) {
    ((unsigned short*)h_hi)[idx] = 0;
    ((unsigned short*)h_lo)[idx] = 0;
  }
  if (tid < 256) {
    bhh_s[tid] = bhh[tid];
    if (tid < 256) { bhh_s[256 + tid] = bhh[256 + tid]; bhh_s[512 + tid] = bhh[512 + tid]; }
  }
  if (MODE == 1 && tid < 16) len_s[tid] = lengths[ub + tid];

  // preload whh-hi fragments (persistent registers, 192 VGPRs)
  v8s whi[6][8];
  int voff = r * 256 + g * 8;              // per-lane weight offset (1 VGPR)
  #pragma unroll
  for (int tt = 0; tt < 6; tt++)
    #pragma unroll
    for (int kk = 0; kk < 8; kk++)
      whi[tt][kk] = *(const v8s*)&whi_g[(wv * 6 + tt) * 4096 + kk * 32 + voff];
  __syncthreads();

  for (int t = 0; t < TT; t++) {
    // ---- async-stage gi(t) into LDS (overlaps with MFMA phase) ----
    {
      int u0 = wv * 2;
      #pragma unroll
      for (int c = 0; c < 6; c++) {
        int uu = u0 + (c >= 3), ch = (c >= 3) ? (c - 3) : c;
        const float* gsrc = gi + ((size_t)(ub + uu) * TT + t) * G3 + ch * 256 + l * 4;
        async_copy16(gsrc, &gi_lds[uu][ch * 256]);
      }
    }
    // ---- MM: gh = h @ whh^T (bias deferred to gates) ----
    v4f acc[6];
    #pragma unroll
    for (int tt = 0; tt < 6; tt++) acc[tt] = (v4f){0.f, 0.f, 0.f, 0.f};
    #pragma unroll
    for (int kk = 0; kk < 8; kk++) {
      int slot = ((kk * 4 + g) ^ (r & 7)) * 8;
      v8s ahi = *(const v8s*)&h_hi[r][slot];
      v8s alo = *(const v8s*)&h_lo[r][slot];
      #pragma unroll
      for (int tt = 0; tt < 6; tt++) {
        v8s blo = *(const v8s*)&wlo_g[(wv * 6 + tt) * 4096 + kk * 32 + voff];
        acc[tt] = __builtin_amdgcn_mfma_f32_16x16x32_bf16(ahi, whi[tt][kk], acc[tt], 0, 0, 0);
        acc[tt] = __builtin_amdgcn_mfma_f32_16x16x32_bf16(alo, whi[tt][kk], acc[tt], 0, 0, 0);
        acc[tt] = __builtin_amdgcn_mfma_f32_16x16x32_bf16(ahi, blo,         acc[tt], 0, 0, 0);
      }
    }
    // ---- scatter gh to bufA ----
    #pragma unroll
    for (int tt = 0; tt < 6; tt++) {
      int tau = wv * 6 + tt;
      int off = ((tau & 15) * 2 + (r >> 3)) * 25 + (tau >> 4) * 8 + (r & 7);
      #pragma unroll
      for (int i = 0; i < 4; i++)
        bufA[(g * 4 + i) * 800 + off] = acc[tt][i];
    }
    __syncthreads();                     // also drains gi_lds async loads
    // ---- gates (per-element LDS reads keep register pressure low) ----
    int bb = (u * 32 + j8) * 25;
    int slot8 = (j8 ^ (u & 7)) * 8;
    v8s hi_vec, lo_vec;
    #pragma unroll
    for (int i = 0; i < 8; i++) {
      int jj = j8 * 8 + i;
      float ir  = gi_lds[u][jj]        ;
      float iz  = gi_lds[u][256 + jj]  ;
      float inn = gi_lds[u][512 + jj]  ;
      float hr = bufA[bb + i]      + bhh_s[jj];
      float hz = bufA[bb + 8 + i]  + bhh_s[256 + jj];
      float hn = bufA[bb + 16 + i] + bhh_s[512 + jj];
      float rr = 1.f / (1.f + __expf(-(ir + hr)));
      float zz = 1.f / (1.f + __expf(-(iz + hz)));
      float e  = __expf(2.f * (inn + rr * hn));
      float nn = 1.f - 2.f / (e + 1.f);
      float hold = b2f(h_hi[u][slot8 + i]) + b2f(h_lo[u][slot8 + i]);
      float hnew = (1.f - zz) * nn + zz * hold;
      unsigned short hi_ = f2b(hnew);
      unsigned short lo_ = f2b(hnew - b2f(hi_));
      hi_vec[i] = (short)hi_;
      lo_vec[i] = (short)lo_;
    }
    *(v8s*)&h_hi[u][slot8] = hi_vec;
    *(v8s*)&h_lo[u][slot8] = lo_vec;
    if (MODE == 0) {
      size_t o = ((size_t)(ub + u) * TT + t) * HD + j8 * 8;
      *(v8s*)&hseq_hi[o] = hi_vec;
      *(v8s*)&hseq_lo[o] = lo_vec;
    } else {
      if (t == len_s[u] - 1) {
        float* op = out + (size_t)(ub + u) * HD + j8 * 8;
        #pragma unroll
        for (int i = 0; i < 8; i++)
          op[i] = b2f((unsigned short)hi_vec[i]) + b2f((unsigned short)lo_vec[i]);
      }
    }
    __syncthreads();
  }
}

extern "C" void kernel_launch(void* const* d_in, const int* in_sizes, int n_in,
                              void* d_out, int out_size, void* d_ws, size_t ws_size,
                              hipStream_t stream) {
  const float* prob  = (const float*)d_in[0];
  const int*   seq   = (const int*)d_in[1];
  // d_in[2] = uid (unused by the reference output)
  const float* table = (const float*)d_in[3];
  const float* wih   = (const float*)d_in[4];
  const float* whh   = (const float*)d_in[5];
  const float* bih   = (const float*)d_in[6];
  const float* bhh   = (const float*)d_in[7];
  float* out = (float*)d_out;

  char* ws = (char*)d_ws;
  float* gi            = (float*)ws;                          // 50,331,648 B (gi1, reused as gi2)
  unsigned short* xbhi = (unsigned short*)(ws + 50331648);    // 8 MB
  unsigned short* xblo = (unsigned short*)(ws + 58720256);    // 8 MB
  unsigned short* h1hi = xbhi;   // overlay: xb dead after gemm1, h1 born in recur1
  unsigned short* h1lo = xblo;
  char* wsw = ws + 67108864;
  const size_t WSZ = 393216;                                  // 768*256*2 B
  unsigned short* wih1hi = (unsigned short*)(wsw + 0 * WSZ);
  unsigned short* wih1lo = (unsigned short*)(wsw + 1 * WSZ);
  unsigned short* wih2hi = (unsigned short*)(wsw + 2 * WSZ);
  unsigned short* wih2lo = (unsigned short*)(wsw + 3 * WSZ);
  unsigned short* whh1hi = (unsigned short*)(wsw + 4 * WSZ);
  unsigned short* whh1lo = (unsigned short*)(wsw + 5 * WSZ);
  unsigned short* whh2hi = (unsigned short*)(wsw + 6 * WSZ);
  unsigned short* whh2lo = (unsigned short*)(wsw + 7 * WSZ);
  int* order   = (int*)(wsw + 8 * WSZ);
  int* lengths = order + KU * NBASK;

  k_convert<<<dim3(192, 4), 1024, 0, stream>>>(wih, whh,
      wih1hi, wih1lo, wih2hi, wih2lo, whh1hi, whh1lo, whh2hi, whh2lo);
  k_order<<<dim3(KU), 64, 0, stream>>>(prob, seq, order, lengths);
  k_basket<<<dim3(NBASK, KU), 256, 0, stream>>>(prob, seq, table, order, xbhi, xblo);
  // gi1 = x @ wih1^T + bih1
  k_gemm3<<<dim3(12, 256), 256, 0, stream>>>(xbhi, xblo, wih1hi, wih1lo, bih, gi);
  // layer-1 recurrence -> h1 sequence
  k_recur<0><<<dim3(16), 512, 0, stream>>>(whh1hi, whh1lo, gi, bhh,
                                           nullptr, h1hi, h1lo, nullptr);
  // gi2 = h1 @ wih2^T + bih2  (overwrites gi buffer)
  k_gemm3<<<dim3(12, 256), 256, 0, stream>>>(h1hi, h1lo, wih2hi, wih2lo, bih + G3, gi);
  // layer-2 recurrence -> output at t == len-1
  k_recur<1><<<dim3(16), 512, 0, stream>>>(whh2hi, whh2lo, gi, bhh + G3,
                                           lengths, nullptr, nullptr, out);
}

// Round 5
// 1348.756 us; speedup vs baseline: 3.3674x; 1.6096x over previous
//
#include <hip/hip_runtime.h>
#include <cstdint>

#define KU 256
#define NBASK 64
#define MBS 20
#define BITEMS 1280
#define HD 256
#define G3 768
#define TT 64

typedef short v8s __attribute__((ext_vector_type(8)));
typedef float v4f __attribute__((ext_vector_type(4)));
typedef unsigned short v4us __attribute__((ext_vector_type(4)));

__device__ __forceinline__ unsigned short f2b(float f){
  uint32_t u = __float_as_uint(f);
  u += 0x7FFFu + ((u >> 16) & 1u);
  return (unsigned short)(u >> 16);
}
__device__ __forceinline__ float b2f(unsigned short s){
  return __uint_as_float(((uint32_t)s) << 16);
}
__device__ __forceinline__ void async_copy16(const float* g, float* l){
  __builtin_amdgcn_global_load_lds(
      (const __attribute__((address_space(1))) unsigned int*)g,
      (__attribute__((address_space(3))) unsigned int*)l, 16, 0, 0);
}

// ---------------- weight conversion: fp32 -> bf16 hi + residual lo ---------
__global__ __launch_bounds__(1024) void k_convert(
    const float* __restrict__ wih, const float* __restrict__ whh,
    unsigned short* __restrict__ wih1hi, unsigned short* __restrict__ wih1lo,
    unsigned short* __restrict__ wih2hi, unsigned short* __restrict__ wih2lo,
    unsigned short* __restrict__ whh1hi, unsigned short* __restrict__ whh1lo,
    unsigned short* __restrict__ whh2hi, unsigned short* __restrict__ whh2lo)
{
  int idx = blockIdx.x * 1024 + threadIdx.x;     // 0..196607
  int which = blockIdx.y;
  float v;
  if (which == 0)      v = wih[idx];
  else if (which == 1) v = wih[196608 + idx];
  else if (which == 2) v = whh[idx];
  else                 v = whh[196608 + idx];
  unsigned short hi = f2b(v);
  unsigned short lo = f2b(v - b2f(hi));
  if (which == 0)      { wih1hi[idx] = hi; wih1lo[idx] = lo; }
  else if (which == 1) { wih2hi[idx] = hi; wih2lo[idx] = lo; }
  else if (which == 2) { whh1hi[idx] = hi; whh1lo[idx] = lo; }
  else                 { whh2hi[idx] = hi; whh2lo[idx] = lo; }
}

// ---------------- per-user basket ordering (stable: valid first) -----------
__global__ __launch_bounds__(64) void k_order(
    const float* __restrict__ prob, const int* __restrict__ seq,
    int* __restrict__ order, int* __restrict__ lengths)
{
  int k = blockIdx.x, j = threadIdx.x;           // j = basket
  int base = k * BITEMS + j * MBS;
  float mx = 0.f;
  #pragma unroll
  for (int m = 0; m < MBS; m++) {
    int it = seq[base + m];
    float p = (it >= 0) ? prob[base + m] : 0.f;
    mx = fmaxf(mx, p);
  }
  bool valid = mx > 0.f;
  unsigned long long bal = __ballot(valid);
  int len = __popcll(bal);
  unsigned long long below = bal & ((1ull << j) - 1ull);
  int pos = valid ? __popcll(below) : (len + (j - __popcll(below)));
  order[k * NBASK + j] = pos;
  if (j == 0) lengths[k] = (len > 0) ? len : 1;
}

// ---------------- basket pooling -> ordered x (bf16 hi+lo) -----------------
__global__ __launch_bounds__(256) void k_basket(
    const float* __restrict__ prob, const int* __restrict__ seq,
    const float* __restrict__ table, const int* __restrict__ order,
    unsigned short* __restrict__ xbhi, unsigned short* __restrict__ xblo)
{
  int j = blockIdx.x, k = blockIdx.y;
  int h = threadIdx.x;
  int base = k * BITEMS + j * MBS;
  float acc = 0.f, sp = 0.f;
  #pragma unroll
  for (int m = 0; m < MBS; m++) {
    int it = seq[base + m];
    if (it >= 0) {
      float p = prob[base + m];
      sp += p;
      acc += p * table[(size_t)(it + 1) * HD + h];
    }
  }
  float val = acc / (sp + 1e-10f);
  int dest = order[k * NBASK + j];
  unsigned short hi = f2b(val);
  size_t o = ((size_t)k * NBASK + dest) * HD + h;
  xbhi[o] = hi;
  xblo[o] = f2b(val - b2f(hi));
}

// ---------------- 3-product split-bf16 GEMM: Y = X @ W^T + bias ------------
// X [16384][256] (hi,lo), W [768][256] (hi,lo), Y [16384][768] fp32
__global__ __launch_bounds__(256) void k_gemm3(
    const unsigned short* __restrict__ Xhi, const unsigned short* __restrict__ Xlo,
    const unsigned short* __restrict__ Whi, const unsigned short* __restrict__ Wlo,
    const float* __restrict__ bias, float* __restrict__ Y)
{
  int nblk = blockIdx.x;              // 0..11
  int mblk = blockIdx.y;              // 0..255
  int wv = threadIdx.x >> 6;
  int l = threadIdx.x & 63;
  int r = l & 15, g = l >> 4;
  int mbase = mblk * 64 + wv * 16;
  int nbase = nblk * 64;
  v4f acc[4];
  #pragma unroll
  for (int c = 0; c < 4; c++) {
    float bn = bias[nbase + c * 16 + r];
    acc[c] = (v4f){bn, bn, bn, bn};
  }
  const unsigned short* xh = Xhi + (size_t)(mbase + r) * HD;
  const unsigned short* xl = Xlo + (size_t)(mbase + r) * HD;
  #pragma unroll
  for (int k0 = 0; k0 < HD; k0 += 32) {
    v8s ahi = *(const v8s*)(xh + k0 + g * 8);
    v8s alo = *(const v8s*)(xl + k0 + g * 8);
    #pragma unroll
    for (int c = 0; c < 4; c++) {
      size_t wo = (size_t)(nbase + c * 16 + r) * HD + k0 + g * 8;
      v8s bhi = *(const v8s*)(Whi + wo);
      v8s blo = *(const v8s*)(Wlo + wo);
      acc[c] = __builtin_amdgcn_mfma_f32_16x16x32_bf16(ahi, bhi, acc[c], 0, 0, 0);
      acc[c] = __builtin_amdgcn_mfma_f32_16x16x32_bf16(alo, bhi, acc[c], 0, 0, 0);
      acc[c] = __builtin_amdgcn_mfma_f32_16x16x32_bf16(ahi, blo, acc[c], 0, 0, 0);
    }
  }
  #pragma unroll
  for (int c = 0; c < 4; c++) {
    int n = nbase + c * 16 + r;
    int mrow = mbase + g * 4;
    #pragma unroll
    for (int i = 0; i < 4; i++)
      Y[(size_t)(mrow + i) * G3 + n] = acc[c][i];
  }
}

// ---------------- single-layer GRU recurrence ------------------------------
// 16 blocks x 1024 threads (16 waves, 1 block/CU, 4 waves/SIMD -> 128 VGPR).
// Wave w owns row-tiles {w, 16+w, 32+w} (one per gate): whi[3][8] = 96 VGPRs
// persistent -> fits the 128 cap WITHOUT spill (rounds 2-4 failure mode).
// h kept hi+lo in LDS (both A products); weight-lo streamed from L2 for the
// n-gate tile only (r/z gates tolerate hi-only: sigmoid derivative 0.25).
// MODE 0: publish h(t) sequence (hi+lo). MODE 1: out at t==len-1.
template<int MODE>
__global__ __launch_bounds__(1024) void k_recur(
    const unsigned short* __restrict__ whi_g, const unsigned short* __restrict__ wlo_g,
    const float* __restrict__ gi, const float* __restrict__ bhh,
    const int* __restrict__ lengths,
    unsigned short* __restrict__ hseq_hi, unsigned short* __restrict__ hseq_lo,
    float* __restrict__ out)
{
  __shared__ unsigned short h_hi[16][256], h_lo[16][256];
  __shared__ float bufA[16 * 780];         // gh: [user][row 0..767], stride 780
  __shared__ float gi_lds[16][768];
  __shared__ float bhh_s[768];
  __shared__ int len_s[16];
  int tid = threadIdx.x;
  int l = tid & 63, r = l & 15, g = l >> 4;
  int swv = __builtin_amdgcn_readfirstlane(tid >> 6);   // wave id, SGPR
  int ub = blockIdx.x * 16;

  for (int idx = tid; idx < 4096; idx += 1024) {
    ((unsigned short*)h_hi)[idx] = 0;
    ((unsigned short*)h_lo)[idx] = 0;
  }
  if (tid < 768) bhh_s[tid] = bhh[tid];
  if (MODE == 1 && tid < 16) len_s[tid] = lengths[ub + tid];

  // persistent whh-hi fragments: rows (tt*256 + swv*16 + r), 96 VGPRs
  v8s whi[3][8];
  int voff = r * 256 + g * 8;
  #pragma unroll
  for (int tt = 0; tt < 3; tt++)
    #pragma unroll
    for (int kk = 0; kk < 8; kk++)
      whi[tt][kk] = *(const v8s*)&whi_g[tt * 65536 + swv * 4096 + kk * 32 + voff];
  const unsigned short* wlo_n = wlo_g + 2 * 65536 + swv * 4096;  // n-gate rows
  __syncthreads();
  int mylen = (MODE == 1) ? len_s[swv] : 0;

  for (int t = 0; t < TT; t++) {
    // ---- async-stage gi(t) for user swv (drained by the next barrier) ----
    #pragma unroll
    for (int c = 0; c < 3; c++)
      async_copy16(gi + ((size_t)(ub + swv) * TT + t) * G3 + c * 256 + l * 4,
                   &gi_lds[swv][c * 256]);
    // ---- MM: gh rows {swv*16+r} per gate; A = h (16 users) ----
    v4f acc0 = {0.f,0.f,0.f,0.f}, acc1 = {0.f,0.f,0.f,0.f}, acc2 = {0.f,0.f,0.f,0.f};
    #pragma unroll
    for (int kk = 0; kk < 8; kk++) {
      int slot = ((kk * 4 + g) ^ (r & 7)) * 8;
      v8s ahi = *(const v8s*)&h_hi[r][slot];
      v8s alo = *(const v8s*)&h_lo[r][slot];
      v8s nlo = *(const v8s*)&wlo_n[kk * 32 + voff];
      acc0 = __builtin_amdgcn_mfma_f32_16x16x32_bf16(ahi, whi[0][kk], acc0, 0, 0, 0);
      acc0 = __builtin_amdgcn_mfma_f32_16x16x32_bf16(alo, whi[0][kk], acc0, 0, 0, 0);
      acc1 = __builtin_amdgcn_mfma_f32_16x16x32_bf16(ahi, whi[1][kk], acc1, 0, 0, 0);
      acc1 = __builtin_amdgcn_mfma_f32_16x16x32_bf16(alo, whi[1][kk], acc1, 0, 0, 0);
      acc2 = __builtin_amdgcn_mfma_f32_16x16x32_bf16(ahi, whi[2][kk], acc2, 0, 0, 0);
      acc2 = __builtin_amdgcn_mfma_f32_16x16x32_bf16(alo, whi[2][kk], acc2, 0, 0, 0);
      acc2 = __builtin_amdgcn_mfma_f32_16x16x32_bf16(ahi, nlo,        acc2, 0, 0, 0);
    }
    // ---- scatter gh to bufA: user = g*4+i, j = swv*16 + r (per gate) ----
    #pragma unroll
    for (int i = 0; i < 4; i++) {
      int urow = (g * 4 + i) * 780 + swv * 16 + r;
      bufA[urow]       = acc0[i];
      bufA[urow + 256] = acc1[i];
      bufA[urow + 512] = acc2[i];
    }
    __syncthreads();
    // ---- gates: wave swv = user swv; lane l handles j = 4l..4l+3 ----
    int hbase = ((l >> 1) ^ (swv & 7)) * 8 + (l & 1) * 4;
    int bb = swv * 780;
    v4us hi4, lo4;
    v4f hn4;
    #pragma unroll
    for (int i = 0; i < 4; i++) {
      int j = l * 4 + i;
      float ir  = gi_lds[swv][j];
      float iz  = gi_lds[swv][256 + j];
      float inn = gi_lds[swv][512 + j];
      float hr = bufA[bb + j]       + bhh_s[j];
      float hz = bufA[bb + 256 + j] + bhh_s[256 + j];
      float hn = bufA[bb + 512 + j] + bhh_s[512 + j];
      float rr = 1.f / (1.f + __expf(-(ir + hr)));
      float zz = 1.f / (1.f + __expf(-(iz + hz)));
      float e  = __expf(2.f * (inn + rr * hn));
      float nn = 1.f - 2.f / (e + 1.f);
      float hold = b2f(h_hi[swv][hbase + i]) + b2f(h_lo[swv][hbase + i]);
      float hnew = (1.f - zz) * nn + zz * hold;
      unsigned short h_ = f2b(hnew);
      hi4[i] = h_;
      lo4[i] = f2b(hnew - b2f(h_));
      hn4[i] = hnew;
    }
    *(v4us*)&h_hi[swv][hbase] = hi4;
    *(v4us*)&h_lo[swv][hbase] = lo4;
    if (MODE == 0) {
      size_t o = ((size_t)(ub + swv) * TT + t) * HD + l * 4;
      *(v4us*)&hseq_hi[o] = hi4;
      *(v4us*)&hseq_lo[o] = lo4;
    } else {
      if (t == mylen - 1)
        *(v4f*)&out[(size_t)(ub + swv) * HD + l * 4] = hn4;
    }
    __syncthreads();
  }
}

extern "C" void kernel_launch(void* const* d_in, const int* in_sizes, int n_in,
                              void* d_out, int out_size, void* d_ws, size_t ws_size,
                              hipStream_t stream) {
  const float* prob  = (const float*)d_in[0];
  const int*   seq   = (const int*)d_in[1];
  // d_in[2] = uid (unused by the reference output)
  const float* table = (const float*)d_in[3];
  const float* wih   = (const float*)d_in[4];
  const float* whh   = (const float*)d_in[5];
  const float* bih   = (const float*)d_in[6];
  const float* bhh   = (const float*)d_in[7];
  float* out = (float*)d_out;

  char* ws = (char*)d_ws;
  float* gi            = (float*)ws;                          // 50,331,648 B (gi1, reused as gi2)
  unsigned short* xbhi = (unsigned short*)(ws + 50331648);    // 8 MB
  unsigned short* xblo = (unsigned short*)(ws + 58720256);    // 8 MB
  unsigned short* h1hi = xbhi;   // overlay: xb dead after gemm1, h1 born in recur1
  unsigned short* h1lo = xblo;
  char* wsw = ws + 67108864;
  const size_t WSZ = 393216;                                  // 768*256*2 B
  unsigned short* wih1hi = (unsigned short*)(wsw + 0 * WSZ);
  unsigned short* wih1lo = (unsigned short*)(wsw + 1 * WSZ);
  unsigned short* wih2hi = (unsigned short*)(wsw + 2 * WSZ);
  unsigned short* wih2lo = (unsigned short*)(wsw + 3 * WSZ);
  unsigned short* whh1hi = (unsigned short*)(wsw + 4 * WSZ);
  unsigned short* whh1lo = (unsigned short*)(wsw + 5 * WSZ);
  unsigned short* whh2hi = (unsigned short*)(wsw + 6 * WSZ);
  unsigned short* whh2lo = (unsigned short*)(wsw + 7 * WSZ);
  int* order   = (int*)(wsw + 8 * WSZ);
  int* lengths = order + KU * NBASK;

  k_convert<<<dim3(192, 4), 1024, 0, stream>>>(wih, whh,
      wih1hi, wih1lo, wih2hi, wih2lo, whh1hi, whh1lo, whh2hi, whh2lo);
  k_order<<<dim3(KU), 64, 0, stream>>>(prob, seq, order, lengths);
  k_basket<<<dim3(NBASK, KU), 256, 0, stream>>>(prob, seq, table, order, xbhi, xblo);
  // gi1 = x @ wih1^T + bih1
  k_gemm3<<<dim3(12, 256), 256, 0, stream>>>(xbhi, xblo, wih1hi, wih1lo, bih, gi);
  // layer-1 recurrence -> h1 sequence
  k_recur<0><<<dim3(16), 1024, 0, stream>>>(whh1hi, whh1lo, gi, bhh,
                                            nullptr, h1hi, h1lo, nullptr);
  // gi2 = h1 @ wih2^T + bih2  (overwrites gi buffer)
  k_gemm3<<<dim3(12, 256), 256, 0, stream>>>(h1hi, h1lo, wih2hi, wih2lo, bih + G3, gi);
  // layer-2 recurrence -> output at t == len-1
  k_recur<1><<<dim3(16), 1024, 0, stream>>>(whh2hi, whh2lo, gi, bhh + G3,
                                            lengths, nullptr, nullptr, out);
}